// Round 6
// baseline (105.784 us; speedup 1.0000x reference)
//
#include <hip/hip_runtime.h>
#include <hip/hip_bf16.h>
#include <cstdint>

typedef __bf16 bf16_t;
typedef __attribute__((ext_vector_type(4))) __bf16 bf16x4;
typedef __attribute__((ext_vector_type(8))) __bf16 bf16x8;
typedef __attribute__((ext_vector_type(4))) float f32x4;

#define DIM 256
#define TINV 10.0f
// TINV * log2(e): e = exp(S/T) == exp2(S * EXP2C)
#define EXP2C 14.426950408889634f
#define BM 128
#define BN 128

// Kernel 1: row-normalize y (f32) -> yn (bf16); zero the loss accumulator.
__global__ void nt_normalize(const float* __restrict__ y, bf16_t* __restrict__ yn,
                             float* __restrict__ out, int N) {
    int tid = threadIdx.x;
    int wave = tid >> 6, lane = tid & 63;
    int row = blockIdx.x * 4 + wave;
    float4 v = ((const float4*)(y + (size_t)row * DIM))[lane];
    float ss = v.x * v.x + v.y * v.y + v.z * v.z + v.w * v.w;
#pragma unroll
    for (int off = 1; off < 64; off <<= 1) ss += __shfl_xor(ss, off);
    float inv = 1.0f / fmaxf(sqrtf(ss), 1e-8f);
    bf16x4 o;
    o[0] = (bf16_t)(v.x * inv);
    o[1] = (bf16_t)(v.y * inv);
    o[2] = (bf16_t)(v.z * inv);
    o[3] = (bf16_t)(v.w * inv);
    ((bf16x4*)(yn + (size_t)row * DIM))[lane] = o;
    if (blockIdx.x == 0 && tid == 0) out[0] = 0.0f;   // zero loss accumulator
}

// Kernel 2: BARRIER-FREE direct-register sim-GEMM + exp + partials + pos capture.
// No LDS staging: each wave loads MFMA fragments straight from L2-resident yn.
// Fragment (m,kc): lanes l16 read 16 consecutive rows, lg reads 64 contiguous
// bytes per row -> full 64B-line utilization; 8 base addrs/wave, imm offsets.
// Zero __syncthreads in the K-loop; compiler pipelines loads freely.
// Triangular grid (by<=bx), 128x128 tile, 4 waves (2x2), wave out 64x64.
// No global atomics: single-writer P scheme (row partials -> P[bx][strip by],
// col partials -> P[by][strip bx]).
__launch_bounds__(256, 3)
__global__ void nt_gemm(const bf16_t* __restrict__ yn, float* __restrict__ P,
                        float* __restrict__ posterm, int N) {
    const int nt = N / BN;                      // 64
    const int T = nt * (nt + 1) / 2;            // 2080
    // bijective XCD-chunked swizzle (m204)
    int orig = blockIdx.x;
    int q = T >> 3, r = T & 7;
    int xcd = orig & 7, loc = orig >> 3;
    int t = (xcd < r ? xcd * (q + 1) : r * (q + 1) + (xcd - r) * q) + loc;
    // triangular index -> (by, bx), by <= bx (count from bottom-right corner)
    int s = T - 1 - t;
    float f = sqrtf(8.0f * (float)s + 1.0f);
    int j = (int)((f - 1.0f) * 0.5f);
    while ((j + 1) * (j + 2) / 2 <= s) ++j;
    while (j * (j + 1) / 2 > s) --j;
    int k = s - j * (j + 1) / 2;
    int by = nt - 1 - j, bx = nt - 1 - k;

    int r0 = by * BM, c0 = bx * BN;
    int tid = threadIdx.x;
    int wave = tid >> 6, lane = tid & 63;
    int wr = wave >> 1, wc = wave & 1;
    int l16 = lane & 15, lg = lane >> 4;

    // Per-lane fragment base pointers (bf16x8 = 16B chunk; +lg picks this
    // lane's chunk; kk advances 4 chunks = 64B, folds to imm offset).
    const bf16x8* Ap[4];
    const bf16x8* Bp[4];
#pragma unroll
    for (int m = 0; m < 4; ++m)
        Ap[m] = (const bf16x8*)(yn + (size_t)(r0 + wr * 64 + m * 16 + l16) * DIM) + lg;
#pragma unroll
    for (int n = 0; n < 4; ++n)
        Bp[n] = (const bf16x8*)(yn + (size_t)(c0 + wc * 64 + n * 16 + l16) * DIM) + lg;

    f32x4 acc[4][4] = {};

#pragma unroll 2
    for (int kk = 0; kk < 8; ++kk) {
        bf16x8 af[4], bfr[4];
#pragma unroll
        for (int m = 0; m < 4; ++m) af[m] = Ap[m][kk * 4];
#pragma unroll
        for (int n = 0; n < 4; ++n) bfr[n] = Bp[n][kk * 4];
#pragma unroll
        for (int m = 0; m < 4; ++m)
#pragma unroll
            for (int n = 0; n < 4; ++n)
                acc[m][n] = __builtin_amdgcn_mfma_f32_16x16x32_bf16(
                    af[m], bfr[n], acc[m][n], 0, 0, 0);
    }

    // Epilogue. C/D layout (m89): col = lane&15, row = (lane>>4)*4 + reg.
    __shared__ float rowpart[2][BM];   // [wc][row-in-tile]
    __shared__ float colpart[2][BN];   // [wr][col-in-tile]
    bool diag = (by == bx);
    float colacc[4] = {0.0f, 0.0f, 0.0f, 0.0f};
#pragma unroll
    for (int m = 0; m < 4; ++m) {
#pragma unroll
        for (int r2 = 0; r2 < 4; ++r2) {
            int lrow = wr * 64 + m * 16 + lg * 4 + r2;   // row within tile
            int grow = r0 + lrow;
            float ssum = 0.0f;
#pragma unroll
            for (int n = 0; n < 4; ++n) {
                float S = acc[m][n][r2];
                float e = __builtin_amdgcn_exp2f(S * EXP2C);
                if (diag) {
                    int gcol = c0 + wc * 64 + n * 16 + l16;
                    if (gcol == grow) e = 0.0f;                        // mask diagonal
                    if (gcol == (grow ^ 1)) posterm[grow] = -S * TINV; // positive pair
                }
                ssum += e;
                colacc[n] += e;
            }
            ssum += __shfl_xor(ssum, 1);
            ssum += __shfl_xor(ssum, 2);
            ssum += __shfl_xor(ssum, 4);
            ssum += __shfl_xor(ssum, 8);
            if (l16 == 0) rowpart[wc][lrow] = ssum;
        }
    }
    // col partials: xor 16/32 reduces over this wave's 64 rows
#pragma unroll
    for (int n = 0; n < 4; ++n) {
        colacc[n] += __shfl_xor(colacc[n], 16);
        colacc[n] += __shfl_xor(colacc[n], 32);
    }
    if (!diag && lane < 16) {
#pragma unroll
        for (int n = 0; n < 4; ++n)
            colpart[wr][wc * 64 + n * 16 + lane] = colacc[n];
    }
    __syncthreads();
    // Single-writer stores: threads 0..127 -> row sums, 128..255 -> col sums.
    if (tid < BM) {
        P[(size_t)bx * N + r0 + tid] = rowpart[0][tid] + rowpart[1][tid];
    } else if (!diag) {
        int lcol = tid - BM;
        P[(size_t)by * N + c0 + lcol] = colpart[0][lcol] + colpart[1][lcol];
    }
}

// Kernel 3: loss partial = sum over rows of (posterm[r] + log(sum_slots P[s][r]));
// one row per thread; one atomicAdd per block.
__global__ void nt_reduce(const float* __restrict__ P, const float* __restrict__ posterm,
                          float* __restrict__ out, int N, int nt) {
    int row = blockIdx.x * 256 + threadIdx.x;
    float s = 0.0f;
    for (int j = 0; j < nt; ++j) s += P[(size_t)j * N + row];
    float v = posterm[row] + logf(s);
#pragma unroll
    for (int off = 1; off < 64; off <<= 1) v += __shfl_xor(v, off);
    __shared__ float part[4];
    int wave = threadIdx.x >> 6, lane = threadIdx.x & 63;
    if (lane == 0) part[wave] = v;
    __syncthreads();
    if (threadIdx.x == 0) {
        float tot = part[0] + part[1] + part[2] + part[3];
        atomicAdd(out, tot / (float)N);
    }
}

extern "C" void kernel_launch(void* const* d_in, const int* in_sizes, int n_in,
                              void* d_out, int out_size, void* d_ws, size_t ws_size,
                              hipStream_t stream) {
    const float* y = (const float*)d_in[0];
    int N = in_sizes[0] / DIM;                 // 8192
    int nt = N / BN;                           // 64
    bf16_t* yn = (bf16_t*)d_ws;                // N*DIM bf16 = 4 MB
    float* posterm = (float*)((char*)d_ws + (size_t)N * DIM * sizeof(bf16_t));  // 32 KB
    float* P = posterm + N;                    // nt*N f32 = 2 MB
    float* out = (float*)d_out;

    nt_normalize<<<N / 4, 256, 0, stream>>>(y, yn, out, N);
    int T = nt * (nt + 1) / 2;                 // 2080 blocks, no dead work
    nt_gemm<<<T, 256, 0, stream>>>(yn, P, posterm, N);
    nt_reduce<<<N / 256, 256, 0, stream>>>(P, posterm, out, N, nt);
}

// Round 7
// 70.635 us; speedup vs baseline: 1.4976x; 1.4976x over previous
//
#include <hip/hip_runtime.h>
#include <hip/hip_bf16.h>
#include <cstdint>

typedef __bf16 bf16_t;
typedef __attribute__((ext_vector_type(4))) __bf16 bf16x4;
typedef __attribute__((ext_vector_type(8))) __bf16 bf16x8;
typedef __attribute__((ext_vector_type(4))) float f32x4;

#define DIM 256
#define TINV 10.0f
// TINV * log2(e): e = exp(S/T) == exp2(S * EXP2C)
#define EXP2C 14.426950408889634f
#define BM 128
#define BN 128
#define BK 64

// Kernel 1: row-normalize y (f32) -> yn (bf16); zero the loss accumulator.
__global__ void nt_normalize(const float* __restrict__ y, bf16_t* __restrict__ yn,
                             float* __restrict__ out, int N) {
    int tid = threadIdx.x;
    int wave = tid >> 6, lane = tid & 63;
    int row = blockIdx.x * 4 + wave;
    float4 v = ((const float4*)(y + (size_t)row * DIM))[lane];
    float ss = v.x * v.x + v.y * v.y + v.z * v.z + v.w * v.w;
#pragma unroll
    for (int off = 1; off < 64; off <<= 1) ss += __shfl_xor(ss, off);
    float inv = 1.0f / fmaxf(sqrtf(ss), 1e-8f);
    bf16x4 o;
    o[0] = (bf16_t)(v.x * inv);
    o[1] = (bf16_t)(v.y * inv);
    o[2] = (bf16_t)(v.z * inv);
    o[3] = (bf16_t)(v.w * inv);
    ((bf16x4*)(yn + (size_t)row * DIM))[lane] = o;
    if (blockIdx.x == 0 && tid == 0) out[0] = 0.0f;   // zero loss accumulator
}

// Kernel 2: fused sim-GEMM + exp + partials + pos capture.
// K=256 fully unrolled: 4 BK=64 tiles, double-buffered LDS, COUNTED vmcnt
// (T4) + raw s_barrier — never vmcnt(0) until the last tile; each wait is
// covered by one full compute phase. 128x128 tile, 4 waves (2x2), triangular
// grid (by<=bx), no global atomics (single-writer P scheme).
__launch_bounds__(256, 2)
__global__ void nt_gemm(const bf16_t* __restrict__ yn, float* __restrict__ P,
                        float* __restrict__ posterm, int N) {
    const int nt = N / BN;                      // 64
    const int T = nt * (nt + 1) / 2;            // 2080
    // bijective XCD-chunked swizzle (m204)
    int orig = blockIdx.x;
    int q = T >> 3, r = T & 7;
    int xcd = orig & 7, loc = orig >> 3;
    int t = (xcd < r ? xcd * (q + 1) : r * (q + 1) + (xcd - r) * q) + loc;
    // triangular index -> (by, bx), by <= bx (count from bottom-right corner)
    int s = T - 1 - t;
    float f = sqrtf(8.0f * (float)s + 1.0f);
    int j = (int)((f - 1.0f) * 0.5f);
    while ((j + 1) * (j + 2) / 2 <= s) ++j;
    while (j * (j + 1) / 2 > s) --j;
    int k = s - j * (j + 1) / 2;
    int by = nt - 1 - j, bx = nt - 1 - k;

    __shared__ __align__(16) bf16_t As[2][BM][BK];   // 2 x 16 KB
    __shared__ __align__(16) bf16_t Bs[2][BN][BK];   // 2 x 16 KB
    __shared__ float rowpart[2][BM];
    __shared__ float colpart[2][BN];

    int r0 = by * BM, c0 = bx * BN;
    int tid = threadIdx.x;
    int wave = tid >> 6, lane = tid & 63;
    int wr = wave >> 1, wc = wave & 1;
    int l16 = lane & 15, lg = lane >> 4;

    f32x4 acc[4][4] = {};

    // Stage one K-tile pair into buffer b: 8 global_load_lds per thread.
    // LDS chunk (row, cc) holds global chunk (row, cc ^ (row&7)) [rule #21].
#define STAGE(b, k0)                                                                \
    {                                                                               \
        _Pragma("unroll")                                                           \
        for (int it = 0; it < 4; ++it) {                                            \
            int cbase = it * 256 + wave * 64;                                       \
            int c = cbase + lane;                                                   \
            int row = c >> 3, cc = c & 7;                                           \
            int gc = cc ^ (row & 7);                                                \
            const bf16_t* srcA = yn + (size_t)(r0 + row) * DIM + (k0) + gc * 8;     \
            __builtin_amdgcn_global_load_lds(                                       \
                (const __attribute__((address_space(1))) uint32_t*)srcA,            \
                (__attribute__((address_space(3))) uint32_t*)                       \
                    ((char*)&As[b][0][0] + cbase * 16), 16, 0, 0);                  \
            const bf16_t* srcB = yn + (size_t)(c0 + row) * DIM + (k0) + gc * 8;     \
            __builtin_amdgcn_global_load_lds(                                       \
                (const __attribute__((address_space(1))) uint32_t*)srcB,            \
                (__attribute__((address_space(3))) uint32_t*)                       \
                    ((char*)&Bs[b][0][0] + cbase * 16), 16, 0, 0);                  \
        }                                                                           \
    }

#define COMPUTE(b)                                                                  \
    {                                                                               \
        __builtin_amdgcn_s_setprio(1);                                              \
        _Pragma("unroll")                                                           \
        for (int kk = 0; kk < 2; ++kk) {                                            \
            bf16x8 af[4], bfr[4];                                                   \
            _Pragma("unroll")                                                       \
            for (int m = 0; m < 4; ++m) {                                           \
                int row = wr * 64 + m * 16 + l16;                                   \
                int kc = kk * 4 + lg;                                               \
                af[m] = *(const bf16x8*)((const char*)&As[b][0][0] +                \
                                         row * (BK * 2) + ((kc ^ (row & 7)) * 16)); \
            }                                                                       \
            _Pragma("unroll")                                                       \
            for (int n = 0; n < 4; ++n) {                                           \
                int row = wc * 64 + n * 16 + l16;                                   \
                int kc = kk * 4 + lg;                                               \
                bfr[n] = *(const bf16x8*)((const char*)&Bs[b][0][0] +               \
                                          row * (BK * 2) + ((kc ^ (row & 7)) * 16));\
            }                                                                       \
            _Pragma("unroll")                                                       \
            for (int m = 0; m < 4; ++m)                                             \
                _Pragma("unroll")                                                   \
                for (int n = 0; n < 4; ++n)                                         \
                    acc[m][n] = __builtin_amdgcn_mfma_f32_16x16x32_bf16(            \
                        af[m], bfr[n], acc[m][n], 0, 0, 0);                         \
        }                                                                           \
        __builtin_amdgcn_s_setprio(0);                                              \
    }

#define WAITV(n) asm volatile("s_waitcnt vmcnt(" #n ")" ::: "memory")
#define BAR() __builtin_amdgcn_s_barrier()

    STAGE(0, 0);              // S0: vmcnt 8
    STAGE(1, 64);             // S1: vmcnt 16
    WAITV(8); BAR();          // S0 landed (every wave waits its own 8, then join)
    COMPUTE(0);               // C0 — S1 lands underneath
    BAR();                    // all waves done reading buf0
    STAGE(0, 128);            // S2
    WAITV(8); BAR();          // S1 landed (covered by C0: free)
    COMPUTE(1);               // C1 — S2 lands underneath
    BAR();                    // all waves done reading buf1
    STAGE(1, 192);            // S3
    WAITV(8); BAR();          // S2 landed (covered by C1: free)
    COMPUTE(0);               // C2 — S3 lands underneath
    WAITV(0); BAR();          // S3 landed (covered by C2: free)
    COMPUTE(1);               // C3

#undef STAGE
#undef COMPUTE
#undef WAITV
#undef BAR

    // Epilogue. C/D layout (m89): col = lane&15, row = (lane>>4)*4 + reg.
    bool diag = (by == bx);
    float colacc[4] = {0.0f, 0.0f, 0.0f, 0.0f};
#pragma unroll
    for (int m = 0; m < 4; ++m) {
#pragma unroll
        for (int r2 = 0; r2 < 4; ++r2) {
            int lrow = wr * 64 + m * 16 + lg * 4 + r2;   // row within tile
            int grow = r0 + lrow;
            float ssum = 0.0f;
#pragma unroll
            for (int n = 0; n < 4; ++n) {
                float S = acc[m][n][r2];
                float e = __builtin_amdgcn_exp2f(S * EXP2C);
                if (diag) {
                    int gcol = c0 + wc * 64 + n * 16 + l16;
                    if (gcol == grow) e = 0.0f;                        // mask diagonal
                    if (gcol == (grow ^ 1)) posterm[grow] = -S * TINV; // positive pair
                }
                ssum += e;
                colacc[n] += e;
            }
            ssum += __shfl_xor(ssum, 1);
            ssum += __shfl_xor(ssum, 2);
            ssum += __shfl_xor(ssum, 4);
            ssum += __shfl_xor(ssum, 8);
            if (l16 == 0) rowpart[wc][lrow] = ssum;
        }
    }
    // col partials: xor 16/32 reduces over this wave's 64 rows
#pragma unroll
    for (int n = 0; n < 4; ++n) {
        colacc[n] += __shfl_xor(colacc[n], 16);
        colacc[n] += __shfl_xor(colacc[n], 32);
    }
    if (!diag && lane < 16) {
#pragma unroll
        for (int n = 0; n < 4; ++n)
            colpart[wr][wc * 64 + n * 16 + lane] = colacc[n];
    }
    __syncthreads();
    // Single-writer stores: threads 0..127 -> row sums, 128..255 -> col sums.
    if (tid < BM) {
        P[(size_t)bx * N + r0 + tid] = rowpart[0][tid] + rowpart[1][tid];
    } else if (!diag) {
        int lcol = tid - BM;
        P[(size_t)by * N + c0 + lcol] = colpart[0][lcol] + colpart[1][lcol];
    }
}

// Kernel 3: loss partial = sum over rows of (posterm[r] + log(sum_slots P[s][r]));
// one row per thread; one atomicAdd per block.
__global__ void nt_reduce(const float* __restrict__ P, const float* __restrict__ posterm,
                          float* __restrict__ out, int N, int nt) {
    int row = blockIdx.x * 256 + threadIdx.x;
    float s = 0.0f;
    for (int j = 0; j < nt; ++j) s += P[(size_t)j * N + row];
    float v = posterm[row] + logf(s);
#pragma unroll
    for (int off = 1; off < 64; off <<= 1) v += __shfl_xor(v, off);
    __shared__ float part[4];
    int wave = threadIdx.x >> 6, lane = threadIdx.x & 63;
    if (lane == 0) part[wave] = v;
    __syncthreads();
    if (threadIdx.x == 0) {
        float tot = part[0] + part[1] + part[2] + part[3];
        atomicAdd(out, tot / (float)N);
    }
}

extern "C" void kernel_launch(void* const* d_in, const int* in_sizes, int n_in,
                              void* d_out, int out_size, void* d_ws, size_t ws_size,
                              hipStream_t stream) {
    const float* y = (const float*)d_in[0];
    int N = in_sizes[0] / DIM;                 // 8192
    int nt = N / BN;                           // 64
    bf16_t* yn = (bf16_t*)d_ws;                // N*DIM bf16 = 4 MB
    float* posterm = (float*)((char*)d_ws + (size_t)N * DIM * sizeof(bf16_t));  // 32 KB
    float* P = posterm + N;                    // nt*N f32 = 2 MB
    float* out = (float*)d_out;

    nt_normalize<<<N / 4, 256, 0, stream>>>(y, yn, out, N);
    int T = nt * (nt + 1) / 2;                 // 2080 blocks, no dead work
    nt_gemm<<<T, 256, 0, stream>>>(yn, P, posterm, N);
    nt_reduce<<<N / 256, 256, 0, stream>>>(P, posterm, out, N, nt);
}

// Round 8
// 62.081 us; speedup vs baseline: 1.7040x; 1.1378x over previous
//
#include <hip/hip_runtime.h>
#include <hip/hip_bf16.h>
#include <cstdint>

typedef __bf16 bf16_t;
typedef __attribute__((ext_vector_type(4))) __bf16 bf16x4;
typedef __attribute__((ext_vector_type(8))) __bf16 bf16x8;
typedef __attribute__((ext_vector_type(4))) float f32x4;

#define DIM 256
#define TINV 10.0f
// TINV * log2(e): e = exp(S/T) == exp2(S * EXP2C)
#define EXP2C 14.426950408889634f
#define BM 128
#define BN 128
#define BK 64
#define NSLOT 64   // N/BN, compile-time for full unroll in nt_reduce

// Kernel 1: row-normalize y (f32) -> yn (bf16); zero the loss accumulator.
__global__ void nt_normalize(const float* __restrict__ y, bf16_t* __restrict__ yn,
                             float* __restrict__ out, int N) {
    int tid = threadIdx.x;
    int wave = tid >> 6, lane = tid & 63;
    int row = blockIdx.x * 4 + wave;
    float4 v = ((const float4*)(y + (size_t)row * DIM))[lane];
    float ss = v.x * v.x + v.y * v.y + v.z * v.z + v.w * v.w;
#pragma unroll
    for (int off = 1; off < 64; off <<= 1) ss += __shfl_xor(ss, off);
    float inv = 1.0f / fmaxf(sqrtf(ss), 1e-8f);
    bf16x4 o;
    o[0] = (bf16_t)(v.x * inv);
    o[1] = (bf16_t)(v.y * inv);
    o[2] = (bf16_t)(v.z * inv);
    o[3] = (bf16_t)(v.w * inv);
    ((bf16x4*)(yn + (size_t)row * DIM))[lane] = o;
    if (blockIdx.x == 0 && tid == 0) out[0] = 0.0f;   // zero loss accumulator
}

// Kernel 2: fused sim-GEMM + exp + partials + pos capture.
// Single-buffer 34KB LDS, __launch_bounds__(256,4) -> 4 blocks/CU: while one
// block drains its staging barrier, 3 co-resident blocks issue MFMA (m114
// wave-level overlap). 128x128 tile, 4 waves (2x2), triangular grid (by<=bx),
// no global atomics (single-writer P scheme), XOR-swizzled LDS (rule #21).
__launch_bounds__(256, 4)
__global__ void nt_gemm(const bf16_t* __restrict__ yn, float* __restrict__ P,
                        float* __restrict__ posterm, int N) {
    const int nt = N / BN;                      // 64
    const int T = nt * (nt + 1) / 2;            // 2080
    // bijective XCD-chunked swizzle (m204)
    int orig = blockIdx.x;
    int q = T >> 3, r = T & 7;
    int xcd = orig & 7, loc = orig >> 3;
    int t = (xcd < r ? xcd * (q + 1) : r * (q + 1) + (xcd - r) * q) + loc;
    // triangular index -> (by, bx), by <= bx (count from bottom-right corner)
    int s = T - 1 - t;
    float f = sqrtf(8.0f * (float)s + 1.0f);
    int j = (int)((f - 1.0f) * 0.5f);
    while ((j + 1) * (j + 2) / 2 <= s) ++j;
    while (j * (j + 1) / 2 > s) --j;
    int k = s - j * (j + 1) / 2;
    int by = nt - 1 - j, bx = nt - 1 - k;

    __shared__ __align__(16) bf16_t As[BM][BK];   // 16 KB
    __shared__ __align__(16) bf16_t Bs[BN][BK];   // 16 KB
    __shared__ float rowpart[2][BM];              // 1 KB
    __shared__ float colpart[2][BN];              // 1 KB

    int r0 = by * BM, c0 = bx * BN;
    int tid = threadIdx.x;
    int wave = tid >> 6, lane = tid & 63;
    int wr = wave >> 1, wc = wave & 1;
    int l16 = lane & 15, lg = lane >> 4;

    f32x4 acc[4][4] = {};

    for (int k0 = 0; k0 < DIM; k0 += BK) {
        if (k0) __syncthreads();   // protect previous iter's LDS reads
        // Stage A,B tiles: 128x64 bf16 = 1024 16B-chunks each.
        // LDS chunk (row, cc) holds global chunk (row, cc ^ (row&7)).
#pragma unroll
        for (int it = 0; it < 4; ++it) {
            int cbase = it * 256 + wave * 64;     // wave-uniform chunk base
            int c = cbase + lane;                 // this lane's chunk
            int row = c >> 3, cc = c & 7;
            int gc = cc ^ (row & 7);
            const bf16_t* srcA = yn + (size_t)(r0 + row) * DIM + k0 + gc * 8;
            __builtin_amdgcn_global_load_lds(
                (const __attribute__((address_space(1))) uint32_t*)srcA,
                (__attribute__((address_space(3))) uint32_t*)((char*)&As[0][0] + cbase * 16),
                16, 0, 0);
            const bf16_t* srcB = yn + (size_t)(c0 + row) * DIM + k0 + gc * 8;
            __builtin_amdgcn_global_load_lds(
                (const __attribute__((address_space(1))) uint32_t*)srcB,
                (__attribute__((address_space(3))) uint32_t*)((char*)&Bs[0][0] + cbase * 16),
                16, 0, 0);
        }
        __syncthreads();   // drains vmcnt; co-resident blocks hide the stall

#pragma unroll
        for (int kk = 0; kk < 2; ++kk) {
            bf16x8 af[4], bfr[4];
#pragma unroll
            for (int m = 0; m < 4; ++m) {
                int row = wr * 64 + m * 16 + l16;
                int kc = kk * 4 + lg;
                af[m] = *(const bf16x8*)((const char*)&As[0][0] +
                                         row * (BK * 2) + ((kc ^ (row & 7)) * 16));
            }
#pragma unroll
            for (int n = 0; n < 4; ++n) {
                int row = wc * 64 + n * 16 + l16;
                int kc = kk * 4 + lg;
                bfr[n] = *(const bf16x8*)((const char*)&Bs[0][0] +
                                          row * (BK * 2) + ((kc ^ (row & 7)) * 16));
            }
#pragma unroll
            for (int m = 0; m < 4; ++m)
#pragma unroll
                for (int n = 0; n < 4; ++n)
                    acc[m][n] = __builtin_amdgcn_mfma_f32_16x16x32_bf16(
                        af[m], bfr[n], acc[m][n], 0, 0, 0);
        }
    }

    // Epilogue. C/D layout (m89): col = lane&15, row = (lane>>4)*4 + reg.
    bool diag = (by == bx);
    float colacc[4] = {0.0f, 0.0f, 0.0f, 0.0f};
#pragma unroll
    for (int m = 0; m < 4; ++m) {
#pragma unroll
        for (int r2 = 0; r2 < 4; ++r2) {
            int lrow = wr * 64 + m * 16 + lg * 4 + r2;   // row within tile
            int grow = r0 + lrow;
            float ssum = 0.0f;
#pragma unroll
            for (int n = 0; n < 4; ++n) {
                float S = acc[m][n][r2];
                float e = __builtin_amdgcn_exp2f(S * EXP2C);
                if (diag) {
                    int gcol = c0 + wc * 64 + n * 16 + l16;
                    if (gcol == grow) e = 0.0f;                        // mask diagonal
                    if (gcol == (grow ^ 1)) posterm[grow] = -S * TINV; // positive pair
                }
                ssum += e;
                colacc[n] += e;
            }
            ssum += __shfl_xor(ssum, 1);
            ssum += __shfl_xor(ssum, 2);
            ssum += __shfl_xor(ssum, 4);
            ssum += __shfl_xor(ssum, 8);
            if (l16 == 0) rowpart[wc][lrow] = ssum;
        }
    }
    // col partials: xor 16/32 reduces over this wave's 64 rows
#pragma unroll
    for (int n = 0; n < 4; ++n) {
        colacc[n] += __shfl_xor(colacc[n], 16);
        colacc[n] += __shfl_xor(colacc[n], 32);
    }
    if (!diag && lane < 16) {
#pragma unroll
        for (int n = 0; n < 4; ++n)
            colpart[wr][wc * 64 + n * 16 + lane] = colacc[n];
    }
    __syncthreads();
    // Single-writer stores: threads 0..127 -> row sums, 128..255 -> col sums.
    if (tid < BM) {
        P[(size_t)bx * N + r0 + tid] = rowpart[0][tid] + rowpart[1][tid];
    } else if (!diag) {
        int lcol = tid - BM;
        P[(size_t)by * N + c0 + lcol] = colpart[0][lcol] + colpart[1][lcol];
    }
}

// Kernel 3: loss partial = sum over NSLOT slots (COMPILE-TIME, fully unrolled:
// 64 independent loads in flight instead of a latency-serialized runtime loop).
// 128 blocks x 64 threads, one row per thread; one atomicAdd per wave.
__global__ void nt_reduce(const float* __restrict__ P, const float* __restrict__ posterm,
                          float* __restrict__ out, int N) {
    int row = blockIdx.x * 64 + threadIdx.x;
    float s = 0.0f;
#pragma unroll
    for (int j = 0; j < NSLOT; ++j) s += P[(size_t)j * N + row];
    float v = posterm[row] + logf(s);
#pragma unroll
    for (int off = 1; off < 64; off <<= 1) v += __shfl_xor(v, off);
    if (threadIdx.x == 0) atomicAdd(out, v / (float)N);
}

extern "C" void kernel_launch(void* const* d_in, const int* in_sizes, int n_in,
                              void* d_out, int out_size, void* d_ws, size_t ws_size,
                              hipStream_t stream) {
    const float* y = (const float*)d_in[0];
    int N = in_sizes[0] / DIM;                 // 8192
    int nt = N / BN;                           // 64
    bf16_t* yn = (bf16_t*)d_ws;                // N*DIM bf16 = 4 MB
    float* posterm = (float*)((char*)d_ws + (size_t)N * DIM * sizeof(bf16_t));  // 32 KB
    float* P = posterm + N;                    // nt*N f32 = 2 MB
    float* out = (float*)d_out;

    nt_normalize<<<N / 4, 256, 0, stream>>>(y, yn, out, N);
    int T = nt * (nt + 1) / 2;                 // 2080 blocks, no dead work
    nt_gemm<<<T, 256, 0, stream>>>(yn, P, posterm, N);
    nt_reduce<<<N / 64, 64, 0, stream>>>(P, posterm, out, N);
}